// Round 9
// baseline (1584.836 us; speedup 1.0000x reference)
//
#include <hip/hip_runtime.h>
#include <cstddef>
#include <cstdint>

namespace {

constexpr int H  = 512;
constexpr int V  = 32000;
constexpr int B  = 64;
constexpr int S  = 64;
constexpr int T  = 32;
constexpr int TQ = 32;

typedef unsigned short ushort_t;
typedef __attribute__((ext_vector_type(8))) short bf16x8;
typedef __attribute__((ext_vector_type(4))) short bf16x4;
typedef __attribute__((ext_vector_type(4))) float f32x4;

__device__ __forceinline__ ushort_t f2bf(float f) {
  union { float f; unsigned u; } v; v.f = f;
  return (ushort_t)((v.u + 0x7FFFu + ((v.u >> 16) & 1u)) >> 16);
}

__device__ __forceinline__ float sigm(float x) { return 1.f / (1.f + expf(-x)); }

__device__ __forceinline__ bf16x8 pack8(f32x4 a, f32x4 b) {
  bf16x8 r;
  r[0] = (short)f2bf(a[0]); r[1] = (short)f2bf(a[1]);
  r[2] = (short)f2bf(a[2]); r[3] = (short)f2bf(a[3]);
  r[4] = (short)f2bf(b[0]); r[5] = (short)f2bf(b[1]);
  r[6] = (short)f2bf(b[2]); r[7] = (short)f2bf(b[3]);
  return r;
}
__device__ __forceinline__ bf16x4 pack4(f32x4 a) {
  bf16x4 r;
  r[0] = (short)f2bf(a[0]); r[1] = (short)f2bf(a[1]);
  r[2] = (short)f2bf(a[2]); r[3] = (short)f2bf(a[3]);
  return r;
}

// ---- cross-XCD coherent data movement (round-5..8 proven) ------------------
__device__ __forceinline__ f32x4 load4c(const float* p) {
  f32x4 v;
  asm volatile("global_load_dwordx4 %0, %1, off sc0 sc1" : "=v"(v) : "v"(p));
  return v;
}
__device__ __forceinline__ float load1c(const float* p) {
  float v;
  asm volatile("global_load_dword %0, %1, off sc0 sc1" : "=v"(v) : "v"(p));
  return v;
}
__device__ __forceinline__ void store1c(float* p, float v) {
  asm volatile("global_store_dword %0, %1, off sc0 sc1" :: "v"(p), "v"(v) : "memory");
}
__device__ __forceinline__ void store1cu(unsigned* p, unsigned v) {
  asm volatile("global_store_dword %0, %1, off sc0 sc1" :: "v"(p), "v"(v) : "memory");
}
__device__ __forceinline__ void waitvm0() {
  asm volatile("s_waitcnt vmcnt(0)" ::: "memory");
  __builtin_amdgcn_sched_barrier(0);
}

// Flag barrier (round-9): per-producer flag words 128B apart. Producer:
// waitvm (data acked at coherence point) -> syncthreads -> t0 stores s+1.
// Consumer: wave0 lanes 0..7 poll the 8 flags in parallel (one RTT per
// iteration), __all + s_sleep(1); one syncthreads releases the WG.
// Replaces the serialized 8-deep atomic-RMW counter of rounds 5-8.
__device__ __forceinline__ void flag_barrier(unsigned* flags, int rank,
                                             unsigned step1, int t, int lane, int wv) {
  waitvm0();
  __syncthreads();
  if (t == 0) store1cu(flags + rank * 32, step1);
  if (wv == 0) {
    const unsigned* fp = flags + (lane & 7) * 32;
    for (;;) {
      unsigned v;
      asm volatile("global_load_dword %0, %1, off sc0 sc1" : "=v"(v) : "v"(fp));
      asm volatile("s_waitcnt vmcnt(0)" ::: "memory");
      const int ok = (lane >= 8) || (v >= step1);
      if (__all(ok)) break;
      __builtin_amdgcn_s_sleep(1);
    }
  }
  __syncthreads();
}

// ---------------------------------------------------------------------------
// Embedding + positional encoding
// ---------------------------------------------------------------------------
__global__ __launch_bounds__(256) void k_embed_facts(const int* __restrict__ ctx,
                                                     const float* __restrict__ emb,
                                                     float* __restrict__ facts_in) {
  const int bs = blockIdx.x;
  const int s  = bs & (S - 1);
  const int t  = threadIdx.x;
  __shared__ int sidx[T];
  if (t < T) sidx[t] = ctx[(size_t)bs * T + t];
  __syncthreads();
  float a0 = 0.f, a1 = 0.f;
  for (int tt = 0; tt < T; ++tt) {
    const int ix = sidx[tt];
    if (ix != 0) {
      const float* e = emb + ((size_t)ix << 9);
      a0 += e[t];
      a1 += e[t + 256];
    }
  }
  const float sf = (float)s * (1.f / 64.f);
  const float c1 = 1.f - sf;
  const float c2 = (1.f - 2.f * sf) * (1.f / 512.f);
  facts_in[((size_t)bs << 9) + t]       = a0 * (c1 - (float)t * c2);
  facts_in[((size_t)bs << 9) + t + 256] = a1 * (c1 - (float)(t + 256) * c2);
}

__global__ __launch_bounds__(256) void k_embed_q(const int* __restrict__ qidx,
                                                 const float* __restrict__ emb,
                                                 float* __restrict__ qe) {
  const int bt = blockIdx.x;
  const int t  = threadIdx.x;
  const int ix = qidx[bt];
  float v0 = 0.f, v1 = 0.f;
  if (ix != 0) {
    const float* e = emb + ((size_t)ix << 9);
    v0 = e[t];
    v1 = e[t + 256];
  }
  qe[((size_t)bt << 9) + t]       = v0;
  qe[((size_t)bt << 9) + t + 256] = v1;
}

__global__ __launch_bounds__(256) void k_transpose512(const float* __restrict__ src,
                                                      float* __restrict__ dst) {
  __shared__ float tile[32][33];
  const int x0 = blockIdx.x * 32, y0 = blockIdx.y * 32;
  for (int i = threadIdx.y; i < 32; i += 8)
    tile[i][threadIdx.x] = src[(size_t)(y0 + i) * H + x0 + threadIdx.x];
  __syncthreads();
  for (int i = threadIdx.y; i < 32; i += 8)
    dst[(size_t)(x0 + i) * H + y0 + threadIdx.x] = tile[threadIdx.x][i];
}

// ---------------------------------------------------------------------------
// bf16 MFMA GEMM (NT), validated in round 2 — f32-input variant.
// ---------------------------------------------------------------------------
template <int ACT>
__global__ __launch_bounds__(256) void k_gemm_mfma(const float* __restrict__ Af,
                                                   const float* __restrict__ Bm,
                                                   const float* __restrict__ bias,
                                                   float* __restrict__ C,
                                                   int M, int N, int K) {
  __shared__ __align__(16) ushort_t As[64][72];
  __shared__ __align__(16) ushort_t Bs[64][72];
  const int t    = threadIdx.x;
  const int lane = t & 63;
  const int w    = t >> 6;
  const int wr   = w >> 1, wc = w & 1;
  const int m0 = blockIdx.y << 6, n0 = blockIdx.x << 6;
  const int row = t >> 2;
  const int ch  = t & 3;

  f32x4 acc[2][2] = {};

  for (int k0 = 0; k0 < K; k0 += 64) {
#pragma unroll
    for (int cc = 0; cc < 2; ++cc) {
      const int c8 = ch + cc * 4;
      const float* src = Af + (size_t)(m0 + row) * K + k0 + c8 * 8;
      *(bf16x8*)&As[row][c8 * 8] = pack8(*(const f32x4*)src, *(const f32x4*)(src + 4));
      const float* srb = Bm + (size_t)(n0 + row) * K + k0 + c8 * 8;
      *(bf16x8*)&Bs[row][c8 * 8] = pack8(*(const f32x4*)srb, *(const f32x4*)(srb + 4));
    }
    __syncthreads();
#pragma unroll
    for (int ks = 0; ks < 2; ++ks) {
      bf16x8 a[2], b[2];
#pragma unroll
      for (int fr = 0; fr < 2; ++fr)
        a[fr] = *(const bf16x8*)&As[wr * 32 + fr * 16 + (lane & 15)][ks * 32 + (lane >> 4) * 8];
#pragma unroll
      for (int fc = 0; fc < 2; ++fc)
        b[fc] = *(const bf16x8*)&Bs[wc * 32 + fc * 16 + (lane & 15)][ks * 32 + (lane >> 4) * 8];
#pragma unroll
      for (int fr = 0; fr < 2; ++fr)
#pragma unroll
        for (int fc = 0; fc < 2; ++fc)
          acc[fr][fc] = __builtin_amdgcn_mfma_f32_16x16x32_bf16(a[fr], b[fc], acc[fr][fc], 0, 0, 0);
    }
    __syncthreads();
  }
#pragma unroll
  for (int fr = 0; fr < 2; ++fr) {
#pragma unroll
    for (int fc = 0; fc < 2; ++fc) {
      const int rbase = m0 + wr * 32 + fr * 16 + ((lane >> 4) << 2);
      const int col   = n0 + wc * 32 + fc * 16 + (lane & 15);
      const float bv  = bias ? bias[col] : 0.f;
#pragma unroll
      for (int j = 0; j < 4; ++j) {
        float v = acc[fr][fc][j] + bv;
        if (ACT == 1) v = tanhf(v);
        if (ACT == 2) v = fmaxf(v, 0.f);
        C[(size_t)(rbase + j) * N + col] = v;
      }
    }
  }
}

// ---------------------------------------------------------------------------
// z1 GEMM with fused z-build (round-9): A[bs][k] computed on the fly from
// facts/q/M; seg = k0>>9 selects {f*q, f*M, |f-q|, |f-M|}. M=4096,N=512,K=2048.
// b = blockIdx.y (64 tile rows = one batch item group of bs).
// ---------------------------------------------------------------------------
__global__ __launch_bounds__(256) void k_gemm_z1(const float* __restrict__ facts,
                                                 const float* __restrict__ qv,
                                                 const float* __restrict__ Mv,
                                                 const float* __restrict__ Bm,
                                                 const float* __restrict__ bias,
                                                 float* __restrict__ C) {
  constexpr int N = 512, K = 2048;
  __shared__ __align__(16) ushort_t As[64][72];
  __shared__ __align__(16) ushort_t Bs[64][72];
  const int t    = threadIdx.x;
  const int lane = t & 63;
  const int w    = t >> 6;
  const int wr   = w >> 1, wc = w & 1;
  const int m0 = blockIdx.y << 6, n0 = blockIdx.x << 6;
  const int row = t >> 2;
  const int ch  = t & 3;
  const int b   = blockIdx.y;          // bs>>6, uniform for this block

  f32x4 acc[2][2] = {};

  for (int k0 = 0; k0 < K; k0 += 64) {
    const int seg = k0 >> 9;
    const int kb  = k0 & 511;
    const float* other = ((seg & 1) ? Mv : qv) + ((size_t)b << 9);
#pragma unroll
    for (int cc = 0; cc < 2; ++cc) {
      const int c8 = ch + cc * 4;
      const int kk = kb + c8 * 8;
      const float* fp = facts + ((size_t)(m0 + row) << 9) + kk;
      const f32x4 f0 = *(const f32x4*)fp;
      const f32x4 f1 = *(const f32x4*)(fp + 4);
      const f32x4 o0 = *(const f32x4*)(other + kk);
      const f32x4 o1 = *(const f32x4*)(other + kk + 4);
      f32x4 z0, z1;
      if (seg < 2) {
        z0 = f0 * o0; z1 = f1 * o1;
      } else {
        z0 = f0 - o0; z1 = f1 - o1;
#pragma unroll
        for (int e = 0; e < 4; ++e) { z0[e] = fabsf(z0[e]); z1[e] = fabsf(z1[e]); }
      }
      *(bf16x8*)&As[row][c8 * 8] = pack8(z0, z1);
      const float* srb = Bm + (size_t)(n0 + row) * K + k0 + c8 * 8;
      *(bf16x8*)&Bs[row][c8 * 8] = pack8(*(const f32x4*)srb, *(const f32x4*)(srb + 4));
    }
    __syncthreads();
#pragma unroll
    for (int ks = 0; ks < 2; ++ks) {
      bf16x8 a[2], bb[2];
#pragma unroll
      for (int fr = 0; fr < 2; ++fr)
        a[fr] = *(const bf16x8*)&As[wr * 32 + fr * 16 + (lane & 15)][ks * 32 + (lane >> 4) * 8];
#pragma unroll
      for (int fc = 0; fc < 2; ++fc)
        bb[fc] = *(const bf16x8*)&Bs[wc * 32 + fc * 16 + (lane & 15)][ks * 32 + (lane >> 4) * 8];
#pragma unroll
      for (int fr = 0; fr < 2; ++fr)
#pragma unroll
        for (int fc = 0; fc < 2; ++fc)
          acc[fr][fc] = __builtin_amdgcn_mfma_f32_16x16x32_bf16(a[fr], bb[fc], acc[fr][fc], 0, 0, 0);
    }
    __syncthreads();
  }
#pragma unroll
  for (int fr = 0; fr < 2; ++fr) {
#pragma unroll
    for (int fc = 0; fc < 2; ++fc) {
      const int rbase = m0 + wr * 32 + fr * 16 + ((lane >> 4) << 2);
      const int col   = n0 + wc * 32 + fc * 16 + (lane & 15);
      const float bv  = bias[col];
#pragma unroll
      for (int j = 0; j < 4; ++j)
        C[(size_t)(rbase + j) * N + col] = tanhf(acc[fr][fc][j] + bv);
    }
  }
}

// ---------------------------------------------------------------------------
// nm GEMM with fused concat3 (round-9): A[64][1536] = [M | C | q]. relu.
// ---------------------------------------------------------------------------
__global__ __launch_bounds__(256) void k_gemm_cat3(const float* __restrict__ Mv,
                                                   const float* __restrict__ Cv,
                                                   const float* __restrict__ qv,
                                                   const float* __restrict__ Bm,
                                                   const float* __restrict__ bias,
                                                   float* __restrict__ C) {
  constexpr int N = 512, K = 1536;
  __shared__ __align__(16) ushort_t As[64][72];
  __shared__ __align__(16) ushort_t Bs[64][72];
  const int t    = threadIdx.x;
  const int lane = t & 63;
  const int w    = t >> 6;
  const int wr   = w >> 1, wc = w & 1;
  const int n0 = blockIdx.x << 6;
  const int row = t >> 2;
  const int ch  = t & 3;

  f32x4 acc[2][2] = {};

  for (int k0 = 0; k0 < K; k0 += 64) {
    const int seg = k0 >> 9;
    const float* src = (seg == 0) ? Mv : (seg == 1) ? Cv : qv;
    const int kb = k0 & 511;
#pragma unroll
    for (int cc = 0; cc < 2; ++cc) {
      const int c8 = ch + cc * 4;
      const float* fp = src + ((size_t)row << 9) + kb + c8 * 8;
      *(bf16x8*)&As[row][c8 * 8] = pack8(*(const f32x4*)fp, *(const f32x4*)(fp + 4));
      const float* srb = Bm + (size_t)(n0 + row) * K + k0 + c8 * 8;
      *(bf16x8*)&Bs[row][c8 * 8] = pack8(*(const f32x4*)srb, *(const f32x4*)(srb + 4));
    }
    __syncthreads();
#pragma unroll
    for (int ks = 0; ks < 2; ++ks) {
      bf16x8 a[2], bb[2];
#pragma unroll
      for (int fr = 0; fr < 2; ++fr)
        a[fr] = *(const bf16x8*)&As[wr * 32 + fr * 16 + (lane & 15)][ks * 32 + (lane >> 4) * 8];
#pragma unroll
      for (int fc = 0; fc < 2; ++fc)
        bb[fc] = *(const bf16x8*)&Bs[wc * 32 + fc * 16 + (lane & 15)][ks * 32 + (lane >> 4) * 8];
#pragma unroll
      for (int fr = 0; fr < 2; ++fr)
#pragma unroll
        for (int fc = 0; fc < 2; ++fc)
          acc[fr][fc] = __builtin_amdgcn_mfma_f32_16x16x32_bf16(a[fr], bb[fc], acc[fr][fc], 0, 0, 0);
    }
    __syncthreads();
  }
#pragma unroll
  for (int fr = 0; fr < 2; ++fr) {
#pragma unroll
    for (int fc = 0; fc < 2; ++fc) {
      const int rbase = wr * 32 + fr * 16 + ((lane >> 4) << 2);
      const int col   = n0 + wc * 32 + fc * 16 + (lane & 15);
      const float bv  = bias[col];
#pragma unroll
      for (int j = 0; j < 4; ++j)
        C[(size_t)(rbase + j) * N + col] = fmaxf(acc[fr][fc][j] + bv, 0.f);
    }
  }
}

// ---------------------------------------------------------------------------
// answer GEMM with fused concat2 (round-9): A[64][1024] = [M | q]. N=32000.
// ---------------------------------------------------------------------------
__global__ __launch_bounds__(256) void k_gemm_cat2(const float* __restrict__ Mv,
                                                   const float* __restrict__ qv,
                                                   const float* __restrict__ Bm,
                                                   const float* __restrict__ bias,
                                                   float* __restrict__ C) {
  constexpr int N = 32000, K = 1024;
  __shared__ __align__(16) ushort_t As[64][72];
  __shared__ __align__(16) ushort_t Bs[64][72];
  const int t    = threadIdx.x;
  const int lane = t & 63;
  const int w    = t >> 6;
  const int wr   = w >> 1, wc = w & 1;
  const int n0 = blockIdx.x << 6;
  const int row = t >> 2;
  const int ch  = t & 3;

  f32x4 acc[2][2] = {};

  for (int k0 = 0; k0 < K; k0 += 64) {
    const float* src = (k0 < 512) ? Mv : qv;
    const int kb = k0 & 511;
#pragma unroll
    for (int cc = 0; cc < 2; ++cc) {
      const int c8 = ch + cc * 4;
      const float* fp = src + ((size_t)row << 9) + kb + c8 * 8;
      *(bf16x8*)&As[row][c8 * 8] = pack8(*(const f32x4*)fp, *(const f32x4*)(fp + 4));
      const float* srb = Bm + (size_t)(n0 + row) * K + k0 + c8 * 8;
      *(bf16x8*)&Bs[row][c8 * 8] = pack8(*(const f32x4*)srb, *(const f32x4*)(srb + 4));
    }
    __syncthreads();
#pragma unroll
    for (int ks = 0; ks < 2; ++ks) {
      bf16x8 a[2], bb[2];
#pragma unroll
      for (int fr = 0; fr < 2; ++fr)
        a[fr] = *(const bf16x8*)&As[wr * 32 + fr * 16 + (lane & 15)][ks * 32 + (lane >> 4) * 8];
#pragma unroll
      for (int fc = 0; fc < 2; ++fc)
        bb[fc] = *(const bf16x8*)&Bs[wc * 32 + fc * 16 + (lane & 15)][ks * 32 + (lane >> 4) * 8];
#pragma unroll
      for (int fr = 0; fr < 2; ++fr)
#pragma unroll
        for (int fc = 0; fc < 2; ++fc)
          acc[fr][fc] = __builtin_amdgcn_mfma_f32_16x16x32_bf16(a[fr], bb[fc], acc[fr][fc], 0, 0, 0);
    }
    __syncthreads();
  }
#pragma unroll
  for (int fr = 0; fr < 2; ++fr) {
#pragma unroll
    for (int fc = 0; fc < 2; ++fc) {
      const int rbase = wr * 32 + fr * 16 + ((lane >> 4) << 2);
      const int col   = n0 + wc * 32 + fc * 16 + (lane & 15);
      const float bv  = bias[col];
#pragma unroll
      for (int j = 0; j < 4; ++j)
        C[(size_t)(rbase + j) * N + col] = acc[fr][fc][j] + bv;
    }
  }
}

// ---------------------------------------------------------------------------
// MFMA persistent GRU scan (round-8 proven structure) + round-9 flag barrier
// and gx prefetch. 96 WGs = 12 groups x 8. Plain launch.
// ---------------------------------------------------------------------------
__global__ __launch_bounds__(256, 1) void k_gru_scan_mfma(
    const float* __restrict__ Whh_f, const float* __restrict__ bhh_f,
    const float* __restrict__ Whh_b, const float* __restrict__ bhh_b,
    const float* __restrict__ qWhh,  const float* __restrict__ qbhh,
    const float* __restrict__ gx_f, const float* __restrict__ gx_b,
    const float* __restrict__ gx_q,
    float* __restrict__ Hbuf, float* __restrict__ facts,
    float* __restrict__ hb_all, unsigned* __restrict__ flags_base) {
  const int bx   = blockIdx.x;     // 96
  const int grp  = bx >> 3;        // 0..11
  const int rank = bx & 7;
  const int gru  = grp >> 2;
  const int ib   = grp & 3;        // 16 items each

  const float* Whh; const float* bhh; const float* gx;
  float* H0; float* H1; float* out_seq; int seqlen, rev;
  if (gru == 0)      { Whh = Whh_f; bhh = bhh_f; gx = gx_f; H0 = Hbuf;          H1 = Hbuf + 32768;  out_seq = facts;   seqlen = S;  rev = 0; }
  else if (gru == 1) { Whh = Whh_b; bhh = bhh_b; gx = gx_b; H0 = Hbuf + 65536;  H1 = Hbuf + 98304;  out_seq = hb_all;  seqlen = S;  rev = 1; }
  else               { Whh = qWhh;  bhh = qbhh;  gx = gx_q; H0 = Hbuf + 131072; H1 = Hbuf + 163840; out_seq = nullptr; seqlen = TQ; rev = 0; }

  __shared__ __align__(16) ushort_t hl[16 * 520];   // bf16 h tile, 2-way pad

  const int t    = threadIdx.x;
  const int lane = t & 63;
  const int wv   = t >> 6;
  const int nt   = (rank << 2) + wv;   // 0..31
  const int lm   = lane & 15;
  const int lk   = lane >> 4;          // 0..3
  const int col  = (nt << 4) + lm;

  // pack weight B-fragments once: lane holds Whh[g*512+col][ks*32+lk*8..+8]
  bf16x8 wf[3][16];
#pragma unroll
  for (int g = 0; g < 3; ++g) {
    const float* wrow = Whh + ((size_t)(g * 512 + col) << 9) + (lk << 3);
#pragma unroll
    for (int ks = 0; ks < 16; ++ks) {
      const float* p = wrow + ks * 32;
      wf[g][ks] = pack8(*(const f32x4*)p, *(const f32x4*)(p + 4));
    }
  }
  const float bv0 = bhh[col], bv1 = bhh[512 + col], bv2 = bhh[1024 + col];
  unsigned* flags = flags_base + grp * 8 * 32;

  // initial gx load (step 0)
  float xr[4], xz[4], xn[4];
  {
    const int xidx = rev ? (seqlen - 1) : 0;
#pragma unroll
    for (int j = 0; j < 4; ++j) {
      const int b = (ib << 4) + (lk << 2) + j;
      const size_t gxrow = ((size_t)b * seqlen + xidx) * 1536;
      xr[j] = gx[gxrow + col];
      xz[j] = gx[gxrow + 512 + col];
      xn[j] = gx[gxrow + 1024 + col];
    }
  }

  for (int s = 0; s < seqlen; ++s) {
    float hp[4] = {0.f, 0.f, 0.f, 0.f};
    if (s == 0) {
      for (int i = t; i < 4160; i += 256) ((unsigned*)hl)[i] = 0u;
    } else {
      const float* Hp = (s & 1) ? H1 : H0;
      f32x4 v[8];
#pragma unroll
      for (int u = 0; u < 8; ++u) {
        const int i = (u << 8) + t;            // 0..2047
        v[u] = load4c(Hp + ((size_t)((ib << 4) + (i >> 7)) << 9) + ((i & 127) << 2));
      }
#pragma unroll
      for (int j = 0; j < 4; ++j)
        hp[j] = load1c(Hp + ((size_t)((ib << 4) + (lk << 2) + j) << 9) + col);
      waitvm0();
#pragma unroll
      for (int u = 0; u < 8; ++u) {
        const int i = (u << 8) + t;
        *(bf16x4*)&hl[(i >> 7) * 520 + ((i & 127) << 2)] = pack4(v[u]);
      }
    }
    __syncthreads();

    f32x4 acc0 = {}, acc1 = {}, acc2 = {};
#pragma unroll
    for (int ks = 0; ks < 16; ++ks) {
      const bf16x8 a = *(const bf16x8*)&hl[lm * 520 + (ks << 5) + (lk << 3)];
      acc0 = __builtin_amdgcn_mfma_f32_16x16x32_bf16(a, wf[0][ks], acc0, 0, 0, 0);
      acc1 = __builtin_amdgcn_mfma_f32_16x16x32_bf16(a, wf[1][ks], acc1, 0, 0, 0);
      acc2 = __builtin_amdgcn_mfma_f32_16x16x32_bf16(a, wf[2][ks], acc2, 0, 0, 0);
    }

    const int xidx = rev ? (seqlen - 1 - s) : s;
    float* Hn = (s & 1) ? H0 : H1;
#pragma unroll
    for (int j = 0; j < 4; ++j) {
      const int b = (ib << 4) + (lk << 2) + j;
      const float r = sigm(xr[j] + acc0[j] + bv0);
      const float z = sigm(xz[j] + acc1[j] + bv1);
      const float n = tanhf(xn[j] + r * (acc2[j] + bv2));
      const float hnew = (1.f - z) * n + z * hp[j];
      store1c(Hn + ((size_t)b << 9) + col, hnew);
      if (out_seq) out_seq[((size_t)(b * S + xidx) << 9) + col] = hnew;
    }

    if (s + 1 < seqlen) {
      // prefetch next step's gx (drains under the barrier wait)
      const int xidx2 = rev ? (seqlen - 2 - s) : (s + 1);
      float nxr[4], nxz[4], nxn[4];
#pragma unroll
      for (int j = 0; j < 4; ++j) {
        const int b = (ib << 4) + (lk << 2) + j;
        const size_t gxrow = ((size_t)b * seqlen + xidx2) * 1536;
        nxr[j] = gx[gxrow + col];
        nxz[j] = gx[gxrow + 512 + col];
        nxn[j] = gx[gxrow + 1024 + col];
      }
      flag_barrier(flags, rank, (unsigned)(s + 1), t, lane, wv);
#pragma unroll
      for (int j = 0; j < 4; ++j) { xr[j] = nxr[j]; xz[j] = nxz[j]; xn[j] = nxn[j]; }
    }
  }
}

// ---------------------------------------------------------------------------
// MFMA persistent AGRU scan + flag barrier + input prefetch.
// 32 WGs = 4 groups x 8. Plain launch.
// ---------------------------------------------------------------------------
__global__ __launch_bounds__(256, 1) void k_agru_scan_mfma(
    const float* __restrict__ UrT, const float* __restrict__ UT,
    const float* __restrict__ fRW, const float* __restrict__ fW,
    const float* __restrict__ br, const float* __restrict__ G,
    float* __restrict__ C0, float* __restrict__ C1,
    unsigned* __restrict__ flags_base) {
  const int bx   = blockIdx.x;     // 32
  const int grp  = bx >> 3;        // 0..3 (16 items each)
  const int rank = bx & 7;

  __shared__ __align__(16) ushort_t cl[16 * 520];

  const int t    = threadIdx.x;
  const int lane = t & 63;
  const int wv   = t >> 6;
  const int nt   = (rank << 2) + wv;
  const int lm   = lane & 15;
  const int lk   = lane >> 4;
  const int col  = (nt << 4) + lm;

  bf16x8 wfr[16], wfu[16];
  {
    const float* r0 = UrT + ((size_t)col << 9) + (lk << 3);
    const float* r1 = UT  + ((size_t)col << 9) + (lk << 3);
#pragma unroll
    for (int ks = 0; ks < 16; ++ks) {
      wfr[ks] = pack8(*(const f32x4*)(r0 + ks * 32), *(const f32x4*)(r0 + ks * 32 + 4));
      wfu[ks] = pack8(*(const f32x4*)(r1 + ks * 32), *(const f32x4*)(r1 + ks * 32 + 4));
    }
  }
  const float brv = br[col];
  unsigned* flags = flags_base + grp * 8 * 32;

  // initial step inputs
  float fr[4], fw[4], gg[4];
#pragma unroll
  for (int j = 0; j < 4; ++j) {
    const int b = (grp << 4) + (lk << 2) + j;
    const size_t fi = ((size_t)(b * S) << 9) + col;
    fr[j] = fRW[fi];
    fw[j] = fW[fi];
    gg[j] = G[b << 6];
  }

  for (int s = 0; s < S; ++s) {
    float cp[4] = {0.f, 0.f, 0.f, 0.f};
    if (s == 0) {
      for (int i = t; i < 4160; i += 256) ((unsigned*)cl)[i] = 0u;
    } else {
      const float* Cp = (s & 1) ? C1 : C0;
      f32x4 v[8];
#pragma unroll
      for (int u = 0; u < 8; ++u) {
        const int i = (u << 8) + t;
        v[u] = load4c(Cp + ((size_t)((grp << 4) + (i >> 7)) << 9) + ((i & 127) << 2));
      }
#pragma unroll
      for (int j = 0; j < 4; ++j)
        cp[j] = load1c(Cp + ((size_t)((grp << 4) + (lk << 2) + j) << 9) + col);
      waitvm0();
#pragma unroll
      for (int u = 0; u < 8; ++u) {
        const int i = (u << 8) + t;
        *(bf16x4*)&cl[(i >> 7) * 520 + ((i & 127) << 2)] = pack4(v[u]);
      }
    }
    __syncthreads();

    f32x4 accr = {}, accu = {};
#pragma unroll
    for (int ks = 0; ks < 16; ++ks) {
      const bf16x8 a = *(const bf16x8*)&cl[lm * 520 + (ks << 5) + (lk << 3)];
      accr = __builtin_amdgcn_mfma_f32_16x16x32_bf16(a, wfr[ks], accr, 0, 0, 0);
      accu = __builtin_amdgcn_mfma_f32_16x16x32_bf16(a, wfu[ks], accu, 0, 0, 0);
    }

    float* Cn = (s & 1) ? C0 : C1;
#pragma unroll
    for (int j = 0; j < 4; ++j) {
      const int b = (grp << 4) + (lk << 2) + j;
      const float r  = sigm(fr[j] + accr[j] + brv);
      const float ht = tanhf(fw[j] + r * accu[j] + brv);
      store1c(Cn + ((size_t)b << 9) + col, gg[j] * ht + (1.f - gg[j]) * cp[j]);
    }

    if (s + 1 < S) {
      float nfr[4], nfw[4], ngg[4];
#pragma unroll
      for (int j = 0; j < 4; ++j) {
        const int b = (grp << 4) + (lk << 2) + j;
        const size_t fi = ((size_t)(b * S + s + 1) << 9) + col;
        nfr[j] = fRW[fi];
        nfw[j] = fW[fi];
        ngg[j] = G[(b << 6) + s + 1];
      }
      flag_barrier(flags, rank, (unsigned)(s + 1), t, lane, wv);
#pragma unroll
      for (int j = 0; j < 4; ++j) { fr[j] = nfr[j]; fw[j] = nfw[j]; gg[j] = ngg[j]; }
    }
  }
}

__global__ __launch_bounds__(256) void k_add(float* __restrict__ a, const float* __restrict__ b) {
  const size_t i = (((size_t)blockIdx.x << 8) + threadIdx.x) << 2;
  float4 x = *(float4*)(a + i);
  const float4 y = *(const float4*)(b + i);
  x.x += y.x; x.y += y.y; x.z += y.z; x.w += y.w;
  *(float4*)(a + i) = x;
}

__global__ __launch_bounds__(256) void k_score_softmax(const float* __restrict__ g1,
                                                       const float* __restrict__ z2w,
                                                       const float* __restrict__ z2b,
                                                       float* __restrict__ G) {
  const int b = blockIdx.x, t = threadIdx.x;
  const int wave = t >> 6, lane = t & 63;
  __shared__ float sc[64];
  for (int si = 0; si < 16; ++si) {
    const int s = wave * 16 + si;
    const float* row = g1 + ((size_t)(b * S + s) << 9) + lane * 8;
    const float* w   = z2w + lane * 8;
    float p = 0.f;
#pragma unroll
    for (int k = 0; k < 8; ++k) p += row[k] * w[k];
#pragma unroll
    for (int off = 32; off; off >>= 1) p += __shfl_xor(p, off);
    if (lane == 0) sc[s] = p + z2b[0];
  }
  __syncthreads();
  if (wave == 0) {
    const float v = sc[lane];
    float m = v;
#pragma unroll
    for (int off = 32; off; off >>= 1) m = fmaxf(m, __shfl_xor(m, off));
    const float e = expf(v - m);
    float su = e;
#pragma unroll
    for (int off = 32; off; off >>= 1) su += __shfl_xor(su, off);
    G[(b << 6) + lane] = e / su;
  }
}

}  // namespace

extern "C" void kernel_launch(void* const* d_in, const int* in_sizes, int n_in,
                              void* d_out, int out_size, void* d_ws, size_t ws_size,
                              hipStream_t stream) {
  const int*   contexts  = (const int*)d_in[0];
  const int*   questions = (const int*)d_in[1];
  const float* emb   = (const float*)d_in[2];
  const float* Wih_f = (const float*)d_in[3];
  const float* Whh_f = (const float*)d_in[4];
  const float* bih_f = (const float*)d_in[5];
  const float* bhh_f = (const float*)d_in[6];
  const float* Wih_b = (const float*)d_in[7];
  const float* Whh_b = (const float*)d_in[8];
  const float* bih_b = (const float*)d_in[9];
  const float* bhh_b = (const float*)d_in[10];
  const float* qWih  = (const float*)d_in[11];
  const float* qWhh  = (const float*)d_in[12];
  const float* qbih  = (const float*)d_in[13];
  const float* qbhh  = (const float*)d_in[14];
  const float* Wr    = (const float*)d_in[15];
  const float* Ur    = (const float*)d_in[16];
  const float* br    = (const float*)d_in[17];
  const float* Wm    = (const float*)d_in[18];
  const float* Um    = (const float*)d_in[19];
  const float* z1_w  = (const float*)d_in[20];
  const float* z1_b  = (const float*)d_in[21];
  const float* z2_w  = (const float*)d_in[22];
  const float* z2_b  = (const float*)d_in[23];
  const float* nm_w  = (const float*)d_in[24];
  const float* nm_b  = (const float*)d_in[25];
  const float* ans_w = (const float*)d_in[26];
  const float* ans_b = (const float*)d_in[27];
  (void)in_sizes; (void)n_in; (void)out_size; (void)ws_size;

  float* ws = (float*)d_ws;
  float* WrT      = ws + 0;          // 262144
  float* UrT      = ws + 262144;     // 262144
  float* WT       = ws + 524288;     // 262144
  float* UT       = ws + 786432;     // 262144
  float* facts_in = ws + 1048576;    // 2097152  (reused as fRW)
  float* qe       = ws + 3145728;    // 1048576
  float* gx_f     = ws + 4194304;    // 6291456
  float* gx_b     = ws + 10485760;   // 6291456
  float* gx_q     = ws + 16777216;   // 3145728  (reused as g1)
  float* facts    = ws + 19922944;   // 2097152
  float* hb       = ws + 22020096;   // 2097152  (reused as fW)
  float* Hbuf     = ws + 24117248;   // 196608
  float* C0       = ws + 24313856;   // 32768
  float* C1       = ws + 24346624;   // 32768
  float* M0       = ws + 24379392;   // 32768
  float* M1       = ws + 24412160;   // 32768
  float* Mq       = ws + 24543232;   // flags region (Mq no longer used by GEMMs)
  float* Gm       = ws + 24608768;   // 4096
  float* g1  = gx_q;
  float* fRW = facts_in;
  float* fW  = hb;
  float* preds = (float*)d_out;
  unsigned* bar = (unsigned*)Mq;     // flags: GRU 12*8*32 + 3 hops * 4*8*32 = 6144 u32

  float* q = Hbuf + 131072;          // question GRU final state (TQ even -> H0 slot)

  // ---- flags: zero once per call (monotone counters) ----
  hipMemsetAsync(bar, 0, 6144 * sizeof(unsigned), stream);

  // ---- stage A: embeddings + weight transposes ----
  k_embed_facts<<<B * S, 256, 0, stream>>>(contexts, emb, facts_in);
  k_embed_q<<<B * TQ, 256, 0, stream>>>(questions, emb, qe);
  dim3 tb(32, 8);
  k_transpose512<<<dim3(16, 16), tb, 0, stream>>>(Wr, WrT);
  k_transpose512<<<dim3(16, 16), tb, 0, stream>>>(Ur, UrT);
  k_transpose512<<<dim3(16, 16), tb, 0, stream>>>(Wm, WT);
  k_transpose512<<<dim3(16, 16), tb, 0, stream>>>(Um, UT);

  // ---- stage B: input-side gate GEMMs (bf16 MFMA) ----
  k_gemm_mfma<0><<<dim3(24, 64), 256, 0, stream>>>(facts_in, Wih_f, bih_f, gx_f, 4096, 1536, 512);
  k_gemm_mfma<0><<<dim3(24, 64), 256, 0, stream>>>(facts_in, Wih_b, bih_b, gx_b, 4096, 1536, 512);
  k_gemm_mfma<0><<<dim3(24, 32), 256, 0, stream>>>(qe, qWih, qbih, gx_q, 2048, 1536, 512);

  // ---- stage C: MFMA persistent GRU scans (plain launch, 96 WGs) ----
  k_gru_scan_mfma<<<96, 256, 0, stream>>>(Whh_f, bhh_f, Whh_b, bhh_b, qWhh, qbhh,
                                          gx_f, gx_b, gx_q, Hbuf, facts, hb, bar);
  k_add<<<2048, 256, 0, stream>>>(facts, hb);

  // ---- stage D: hop-invariant precomputes (bf16 MFMA) ----
  k_gemm_mfma<0><<<dim3(8, 64), 256, 0, stream>>>(facts, WrT, nullptr, fRW, 4096, 512, 512);
  k_gemm_mfma<0><<<dim3(8, 64), 256, 0, stream>>>(facts, WT,  nullptr, fW,  4096, 512, 512);

  // ---- stage E: episodic memory hops (fused build_z / concat3) ----
  const float* Mcur = q;
  for (int h = 0; h < 3; ++h) {
    k_gemm_z1<<<dim3(8, 64), 256, 0, stream>>>(facts, q, Mcur, z1_w, z1_b, g1);
    k_score_softmax<<<B, 256, 0, stream>>>(g1, z2_w, z2_b, Gm);
    unsigned* fl = bar + 3072 + h * 1024;
    k_agru_scan_mfma<<<32, 256, 0, stream>>>(UrT, UT, fRW, fW, br, Gm, C0, C1, fl);
    float* Mnext = (h & 1) ? M1 : M0;
    k_gemm_cat3<<<dim3(8, 1), 256, 0, stream>>>(Mcur, C0, q, nm_w, nm_b, Mnext);
    Mcur = Mnext;
  }

  // ---- stage F: answer projection (fused concat2) ----
  k_gemm_cat2<<<dim3(500, 1), 256, 0, stream>>>(Mcur, q, ans_w, ans_b, preds);
}

// Round 10
// 1400.109 us; speedup vs baseline: 1.1319x; 1.1319x over previous
//
#include <hip/hip_runtime.h>
#include <cstddef>
#include <cstdint>

namespace {

constexpr int H  = 512;
constexpr int V  = 32000;
constexpr int B  = 64;
constexpr int S  = 64;
constexpr int T  = 32;
constexpr int TQ = 32;

typedef unsigned short ushort_t;
typedef __attribute__((ext_vector_type(8))) short bf16x8;
typedef __attribute__((ext_vector_type(4))) short bf16x4;
typedef __attribute__((ext_vector_type(4))) float f32x4;
typedef __attribute__((ext_vector_type(4))) unsigned u32x4;

__device__ __forceinline__ ushort_t f2bf(float f) {
  union { float f; unsigned u; } v; v.f = f;
  return (ushort_t)((v.u + 0x7FFFu + ((v.u >> 16) & 1u)) >> 16);
}

__device__ __forceinline__ float sigm(float x) { return 1.f / (1.f + expf(-x)); }

__device__ __forceinline__ bf16x8 pack8(f32x4 a, f32x4 b) {
  bf16x8 r;
  r[0] = (short)f2bf(a[0]); r[1] = (short)f2bf(a[1]);
  r[2] = (short)f2bf(a[2]); r[3] = (short)f2bf(a[3]);
  r[4] = (short)f2bf(b[0]); r[5] = (short)f2bf(b[1]);
  r[6] = (short)f2bf(b[2]); r[7] = (short)f2bf(b[3]);
  return r;
}

// ---- cross-XCD coherent data movement (round-5..9 proven) ------------------
__device__ __forceinline__ u32x4 load16c(const void* p) {
  u32x4 v;
  asm volatile("global_load_dwordx4 %0, %1, off sc0 sc1" : "=v"(v) : "v"(p));
  return v;
}
__device__ __forceinline__ void store2c(ushort_t* p, unsigned v) {
  asm volatile("global_store_short %0, %1, off sc0 sc1" :: "v"(p), "v"(v) : "memory");
}
__device__ __forceinline__ void store1cu(unsigned* p, unsigned v) {
  asm volatile("global_store_dword %0, %1, off sc0 sc1" :: "v"(p), "v"(v) : "memory");
}
__device__ __forceinline__ void waitvm0() {
  asm volatile("s_waitcnt vmcnt(0)" ::: "memory");
  __builtin_amdgcn_sched_barrier(0);
}

// Flag barrier (round-9 proven): per-producer flag words 128B apart.
__device__ __forceinline__ void flag_barrier(unsigned* flags, int rank,
                                             unsigned step1, int t, int lane, int wv) {
  waitvm0();
  __syncthreads();
  if (t == 0) store1cu(flags + rank * 32, step1);
  if (wv == 0) {
    const unsigned* fp = flags + (lane & 7) * 32;
    for (;;) {
      unsigned v;
      asm volatile("global_load_dword %0, %1, off sc0 sc1" : "=v"(v) : "v"(fp));
      asm volatile("s_waitcnt vmcnt(0)" ::: "memory");
      const int ok = (lane >= 8) || (v >= step1);
      if (__all(ok)) break;
      __builtin_amdgcn_s_sleep(1);
    }
  }
  __syncthreads();
}

// ---------------------------------------------------------------------------
// Embedding + positional encoding
// ---------------------------------------------------------------------------
__global__ __launch_bounds__(256) void k_embed_facts(const int* __restrict__ ctx,
                                                     const float* __restrict__ emb,
                                                     float* __restrict__ facts_in) {
  const int bs = blockIdx.x;
  const int s  = bs & (S - 1);
  const int t  = threadIdx.x;
  __shared__ int sidx[T];
  if (t < T) sidx[t] = ctx[(size_t)bs * T + t];
  __syncthreads();
  float a0 = 0.f, a1 = 0.f;
  for (int tt = 0; tt < T; ++tt) {
    const int ix = sidx[tt];
    if (ix != 0) {
      const float* e = emb + ((size_t)ix << 9);
      a0 += e[t];
      a1 += e[t + 256];
    }
  }
  const float sf = (float)s * (1.f / 64.f);
  const float c1 = 1.f - sf;
  const float c2 = (1.f - 2.f * sf) * (1.f / 512.f);
  facts_in[((size_t)bs << 9) + t]       = a0 * (c1 - (float)t * c2);
  facts_in[((size_t)bs << 9) + t + 256] = a1 * (c1 - (float)(t + 256) * c2);
}

__global__ __launch_bounds__(256) void k_embed_q(const int* __restrict__ qidx,
                                                 const float* __restrict__ emb,
                                                 float* __restrict__ qe) {
  const int bt = blockIdx.x;
  const int t  = threadIdx.x;
  const int ix = qidx[bt];
  float v0 = 0.f, v1 = 0.f;
  if (ix != 0) {
    const float* e = emb + ((size_t)ix << 9);
    v0 = e[t];
    v1 = e[t + 256];
  }
  qe[((size_t)bt << 9) + t]       = v0;
  qe[((size_t)bt << 9) + t + 256] = v1;
}

__global__ __launch_bounds__(256) void k_transpose512(const float* __restrict__ src,
                                                      float* __restrict__ dst) {
  __shared__ float tile[32][33];
  const int x0 = blockIdx.x * 32, y0 = blockIdx.y * 32;
  for (int i = threadIdx.y; i < 32; i += 8)
    tile[i][threadIdx.x] = src[(size_t)(y0 + i) * H + x0 + threadIdx.x];
  __syncthreads();
  for (int i = threadIdx.y; i < 32; i += 8)
    dst[(size_t)(x0 + i) * H + y0 + threadIdx.x] = tile[threadIdx.x][i];
}

// ---------------------------------------------------------------------------
// bf16 MFMA GEMM (NT), round-2/8 proven. A: bf16 (A_BF16) or f32.
// ---------------------------------------------------------------------------
template <bool A_BF16, int ACT>
__global__ __launch_bounds__(256) void k_gemm_mfma(const void* __restrict__ Av,
                                                   const float* __restrict__ Bm,
                                                   const float* __restrict__ bias,
                                                   float* __restrict__ C,
                                                   int M, int N, int K) {
  __shared__ __align__(16) ushort_t As[64][72];
  __shared__ __align__(16) ushort_t Bs[64][72];
  const int t    = threadIdx.x;
  const int lane = t & 63;
  const int w    = t >> 6;
  const int wr   = w >> 1, wc = w & 1;
  const int m0 = blockIdx.y << 6, n0 = blockIdx.x << 6;
  const int row = t >> 2;
  const int ch  = t & 3;

  f32x4 acc[2][2] = {};

  for (int k0 = 0; k0 < K; k0 += 64) {
    if (A_BF16) {
      const ushort_t* A16 = (const ushort_t*)Av;
#pragma unroll
      for (int cc = 0; cc < 2; ++cc) {
        const int c8 = ch + cc * 4;
        const uint4 v = *(const uint4*)(A16 + (size_t)(m0 + row) * K + k0 + c8 * 8);
        *(uint4*)&As[row][c8 * 8] = v;
      }
    } else {
      const float* Af = (const float*)Av;
#pragma unroll
      for (int cc = 0; cc < 2; ++cc) {
        const int c8 = ch + cc * 4;
        const float* src = Af + (size_t)(m0 + row) * K + k0 + c8 * 8;
        *(bf16x8*)&As[row][c8 * 8] = pack8(*(const f32x4*)src, *(const f32x4*)(src + 4));
      }
    }
#pragma unroll
    for (int cc = 0; cc < 2; ++cc) {
      const int c8 = ch + cc * 4;
      const float* srb = Bm + (size_t)(n0 + row) * K + k0 + c8 * 8;
      *(bf16x8*)&Bs[row][c8 * 8] = pack8(*(const f32x4*)srb, *(const f32x4*)(srb + 4));
    }
    __syncthreads();
#pragma unroll
    for (int ks = 0; ks < 2; ++ks) {
      bf16x8 a[2], b[2];
#pragma unroll
      for (int fr = 0; fr < 2; ++fr)
        a[fr] = *(const bf16x8*)&As[wr * 32 + fr * 16 + (lane & 15)][ks * 32 + (lane >> 4) * 8];
#pragma unroll
      for (int fc = 0; fc < 2; ++fc)
        b[fc] = *(const bf16x8*)&Bs[wc * 32 + fc * 16 + (lane & 15)][ks * 32 + (lane >> 4) * 8];
#pragma unroll
      for (int fr = 0; fr < 2; ++fr)
#pragma unroll
        for (int fc = 0; fc < 2; ++fc)
          acc[fr][fc] = __builtin_amdgcn_mfma_f32_16x16x32_bf16(a[fr], b[fc], acc[fr][fc], 0, 0, 0);
    }
    __syncthreads();
  }
#pragma unroll
  for (int fr = 0; fr < 2; ++fr) {
#pragma unroll
    for (int fc = 0; fc < 2; ++fc) {
      const int rbase = m0 + wr * 32 + fr * 16 + ((lane >> 4) << 2);
      const int col   = n0 + wc * 32 + fc * 16 + (lane & 15);
      const float bv  = bias ? bias[col] : 0.f;
#pragma unroll
      for (int j = 0; j < 4; ++j) {
        float v = acc[fr][fc][j] + bv;
        if (ACT == 1) v = tanhf(v);
        if (ACT == 2) v = fmaxf(v, 0.f);
        C[(size_t)(rbase + j) * N + col] = v;
      }
    }
  }
}

// z (bf16) = [f*q, f*M, |f-q|, |f-M|]  (round-8 proven; round-9 fusion reverted)
__global__ __launch_bounds__(256) void k_build_z16(const float* __restrict__ facts,
                                                   const float* __restrict__ q,
                                                   const float* __restrict__ M,
                                                   ushort_t* __restrict__ z) {
  const int bs = blockIdx.x;
  const int b  = bs >> 6;
  const int t  = threadIdx.x;
  const size_t zb = (size_t)bs << 11;
  for (int c = t; c < 512; c += 256) {
    const float f  = facts[((size_t)bs << 9) + c];
    const float qv = q[(b << 9) + c];
    const float mv = M[(b << 9) + c];
    z[zb + c]        = f2bf(f * qv);
    z[zb + 512 + c]  = f2bf(f * mv);
    z[zb + 1024 + c] = f2bf(fabsf(f - qv));
    z[zb + 1536 + c] = f2bf(fabsf(f - mv));
  }
}

// ---------------------------------------------------------------------------
// nm GEMM with fused concat3: A[64][1536] = [M | C | q]. relu. (round-9, kept)
// ---------------------------------------------------------------------------
__global__ __launch_bounds__(256) void k_gemm_cat3(const float* __restrict__ Mv,
                                                   const float* __restrict__ Cv,
                                                   const float* __restrict__ qv,
                                                   const float* __restrict__ Bm,
                                                   const float* __restrict__ bias,
                                                   float* __restrict__ C) {
  constexpr int N = 512, K = 1536;
  __shared__ __align__(16) ushort_t As[64][72];
  __shared__ __align__(16) ushort_t Bs[64][72];
  const int t    = threadIdx.x;
  const int lane = t & 63;
  const int w    = t >> 6;
  const int wr   = w >> 1, wc = w & 1;
  const int n0 = blockIdx.x << 6;
  const int row = t >> 2;
  const int ch  = t & 3;

  f32x4 acc[2][2] = {};

  for (int k0 = 0; k0 < K; k0 += 64) {
    const int seg = k0 >> 9;
    const float* src = (seg == 0) ? Mv : (seg == 1) ? Cv : qv;
    const int kb = k0 & 511;
#pragma unroll
    for (int cc = 0; cc < 2; ++cc) {
      const int c8 = ch + cc * 4;
      const float* fp = src + ((size_t)row << 9) + kb + c8 * 8;
      *(bf16x8*)&As[row][c8 * 8] = pack8(*(const f32x4*)fp, *(const f32x4*)(fp + 4));
      const float* srb = Bm + (size_t)(n0 + row) * K + k0 + c8 * 8;
      *(bf16x8*)&Bs[row][c8 * 8] = pack8(*(const f32x4*)srb, *(const f32x4*)(srb + 4));
    }
    __syncthreads();
#pragma unroll
    for (int ks = 0; ks < 2; ++ks) {
      bf16x8 a[2], bb[2];
#pragma unroll
      for (int fr = 0; fr < 2; ++fr)
        a[fr] = *(const bf16x8*)&As[wr * 32 + fr * 16 + (lane & 15)][ks * 32 + (lane >> 4) * 8];
#pragma unroll
      for (int fc = 0; fc < 2; ++fc)
        bb[fc] = *(const bf16x8*)&Bs[wc * 32 + fc * 16 + (lane & 15)][ks * 32 + (lane >> 4) * 8];
#pragma unroll
      for (int fr = 0; fr < 2; ++fr)
#pragma unroll
        for (int fc = 0; fc < 2; ++fc)
          acc[fr][fc] = __builtin_amdgcn_mfma_f32_16x16x32_bf16(a[fr], bb[fc], acc[fr][fc], 0, 0, 0);
    }
    __syncthreads();
  }
#pragma unroll
  for (int fr = 0; fr < 2; ++fr) {
#pragma unroll
    for (int fc = 0; fc < 2; ++fc) {
      const int rbase = wr * 32 + fr * 16 + ((lane >> 4) << 2);
      const int col   = n0 + wc * 32 + fc * 16 + (lane & 15);
      const float bv  = bias[col];
#pragma unroll
      for (int j = 0; j < 4; ++j)
        C[(size_t)(rbase + j) * N + col] = fmaxf(acc[fr][fc][j] + bv, 0.f);
    }
  }
}

// ---------------------------------------------------------------------------
// answer GEMM with fused concat2: A[64][1024] = [M | q]. N=32000. (kept)
// ---------------------------------------------------------------------------
__global__ __launch_bounds__(256) void k_gemm_cat2(const float* __restrict__ Mv,
                                                   const float* __restrict__ qv,
                                                   const float* __restrict__ Bm,
                                                   const float* __restrict__ bias,
                                                   float* __restrict__ C) {
  constexpr int N = 32000, K = 1024;
  __shared__ __align__(16) ushort_t As[64][72];
  __shared__ __align__(16) ushort_t Bs[64][72];
  const int t    = threadIdx.x;
  const int lane = t & 63;
  const int w    = t >> 6;
  const int wr   = w >> 1, wc = w & 1;
  const int n0 = blockIdx.x << 6;
  const int row = t >> 2;
  const int ch  = t & 3;

  f32x4 acc[2][2] = {};

  for (int k0 = 0; k0 < K; k0 += 64) {
    const float* src = (k0 < 512) ? Mv : qv;
    const int kb = k0 & 511;
#pragma unroll
    for (int cc = 0; cc < 2; ++cc) {
      const int c8 = ch + cc * 4;
      const float* fp = src + ((size_t)row << 9) + kb + c8 * 8;
      *(bf16x8*)&As[row][c8 * 8] = pack8(*(const f32x4*)fp, *(const f32x4*)(fp + 4));
      const float* srb = Bm + (size_t)(n0 + row) * K + k0 + c8 * 8;
      *(bf16x8*)&Bs[row][c8 * 8] = pack8(*(const f32x4*)srb, *(const f32x4*)(srb + 4));
    }
    __syncthreads();
#pragma unroll
    for (int ks = 0; ks < 2; ++ks) {
      bf16x8 a[2], bb[2];
#pragma unroll
      for (int fr = 0; fr < 2; ++fr)
        a[fr] = *(const bf16x8*)&As[wr * 32 + fr * 16 + (lane & 15)][ks * 32 + (lane >> 4) * 8];
#pragma unroll
      for (int fc = 0; fc < 2; ++fc)
        bb[fc] = *(const bf16x8*)&Bs[wc * 32 + fc * 16 + (lane & 15)][ks * 32 + (lane >> 4) * 8];
#pragma unroll
      for (int fr = 0; fr < 2; ++fr)
#pragma unroll
        for (int fc = 0; fc < 2; ++fc)
          acc[fr][fc] = __builtin_amdgcn_mfma_f32_16x16x32_bf16(a[fr], bb[fc], acc[fr][fc], 0, 0, 0);
    }
    __syncthreads();
  }
#pragma unroll
  for (int fr = 0; fr < 2; ++fr) {
#pragma unroll
    for (int fc = 0; fc < 2; ++fc) {
      const int rbase = wr * 32 + fr * 16 + ((lane >> 4) << 2);
      const int col   = n0 + wc * 32 + fc * 16 + (lane & 15);
      const float bv  = bias[col];
#pragma unroll
      for (int j = 0; j < 4; ++j)
        C[(size_t)(rbase + j) * N + col] = acc[fr][fc][j] + bv;
    }
  }
}

// ---------------------------------------------------------------------------
// MFMA persistent GRU scan, round-10: bf16 state exchange. The f32 carry hp
// stays in registers (the producing wave IS the consuming wave for its own
// cols); only the bf16 A-operand crosses WGs: 4x2B sc1 stores out,
// 4x16B sc1 loads + direct ds_write_b128 in (no pack, no hp loads).
// 96 WGs = 12 groups (3 gru x 4 ib) x 8. Plain launch.
// ---------------------------------------------------------------------------
__global__ __launch_bounds__(256, 1) void k_gru_scan_mfma(
    const float* __restrict__ Whh_f, const float* __restrict__ bhh_f,
    const float* __restrict__ Whh_b, const float* __restrict__ bhh_b,
    const float* __restrict__ qWhh,  const float* __restrict__ qbhh,
    const float* __restrict__ gx_f, const float* __restrict__ gx_b,
    const float* __restrict__ gx_q,
    ushort_t* __restrict__ H16, float* __restrict__ qbuf,
    float* __restrict__ facts, float* __restrict__ hb_all,
    unsigned* __restrict__ flags_base) {
  const int bx   = blockIdx.x;     // 96
  const int grp  = bx >> 3;        // 0..11
  const int rank = bx & 7;
  const int gru  = grp >> 2;
  const int ib   = grp & 3;        // 16 items each

  const float* Whh; const float* bhh; const float* gx;
  float* out_seq; int seqlen, rev;
  if (gru == 0)      { Whh = Whh_f; bhh = bhh_f; gx = gx_f; out_seq = facts;   seqlen = S;  rev = 0; }
  else if (gru == 1) { Whh = Whh_b; bhh = bhh_b; gx = gx_b; out_seq = hb_all;  seqlen = S;  rev = 1; }
  else               { Whh = qWhh;  bhh = qbhh;  gx = gx_q; out_seq = nullptr; seqlen = TQ; rev = 0; }
  ushort_t* Hb0 = H16 + gru * 65536;   // parity-0 exchange buffer [64][512] bf16
  ushort_t* Hb1 = Hb0 + 32768;

  __shared__ __align__(16) ushort_t hl[16 * 520];

  const int t    = threadIdx.x;
  const int lane = t & 63;
  const int wv   = t >> 6;
  const int nt   = (rank << 2) + wv;   // 0..31
  const int lm   = lane & 15;
  const int lk   = lane >> 4;          // 0..3
  const int col  = (nt << 4) + lm;

  // pack weight B-fragments once
  bf16x8 wf[3][16];
#pragma unroll
  for (int g = 0; g < 3; ++g) {
    const float* wrow = Whh + ((size_t)(g * 512 + col) << 9) + (lk << 3);
#pragma unroll
    for (int ks = 0; ks < 16; ++ks) {
      const float* p = wrow + ks * 32;
      wf[g][ks] = pack8(*(const f32x4*)p, *(const f32x4*)(p + 4));
    }
  }
  const float bv0 = bhh[col], bv1 = bhh[512 + col], bv2 = bhh[1024 + col];
  unsigned* flags = flags_base + grp * 8 * 32;

  // initial gx load (step 0)
  float xr[4], xz[4], xn[4];
  {
    const int xidx = rev ? (seqlen - 1) : 0;
#pragma unroll
    for (int j = 0; j < 4; ++j) {
      const int b = (ib << 4) + (lk << 2) + j;
      const size_t gxrow = ((size_t)b * seqlen + xidx) * 1536;
      xr[j] = gx[gxrow + col];
      xz[j] = gx[gxrow + 512 + col];
      xn[j] = gx[gxrow + 1024 + col];
    }
  }

  float hp[4] = {0.f, 0.f, 0.f, 0.f};   // f32 carry, register-resident

  for (int s = 0; s < seqlen; ++s) {
    if (s == 0) {
      for (int i = t; i < 4160; i += 256) ((unsigned*)hl)[i] = 0u;
    } else {
      const ushort_t* Hp16 = (s & 1) ? Hb1 : Hb0;
      u32x4 v[4];
#pragma unroll
      for (int u = 0; u < 4; ++u) {
        const int i = (u << 8) + t;          // 0..1023, 8 ushorts each
        v[u] = load16c(Hp16 + ((size_t)((ib << 4) + (i >> 6)) << 9) + ((i << 3) & 511));
      }
      waitvm0();
#pragma unroll
      for (int u = 0; u < 4; ++u) {
        const int i = (u << 8) + t;
        *(u32x4*)&hl[(i >> 6) * 520 + ((i << 3) & 511)] = v[u];
      }
    }
    __syncthreads();

    f32x4 acc0 = {}, acc1 = {}, acc2 = {};
#pragma unroll
    for (int ks = 0; ks < 16; ++ks) {
      const bf16x8 a = *(const bf16x8*)&hl[lm * 520 + (ks << 5) + (lk << 3)];
      acc0 = __builtin_amdgcn_mfma_f32_16x16x32_bf16(a, wf[0][ks], acc0, 0, 0, 0);
      acc1 = __builtin_amdgcn_mfma_f32_16x16x32_bf16(a, wf[1][ks], acc1, 0, 0, 0);
      acc2 = __builtin_amdgcn_mfma_f32_16x16x32_bf16(a, wf[2][ks], acc2, 0, 0, 0);
    }

    const int xidx = rev ? (seqlen - 1 - s) : s;
    ushort_t* Hn16 = (s & 1) ? Hb0 : Hb1;
#pragma unroll
    for (int j = 0; j < 4; ++j) {
      const int b = (ib << 4) + (lk << 2) + j;
      const float r = sigm(xr[j] + acc0[j] + bv0);
      const float z = sigm(xz[j] + acc1[j] + bv1);
      const float n = tanhf(xn[j] + r * (acc2[j] + bv2));
      const float hnew = (1.f - z) * n + z * hp[j];
      hp[j] = hnew;
      if (s + 1 < seqlen) store2c(Hn16 + ((size_t)b << 9) + col, (unsigned)f2bf(hnew));
      if (out_seq) out_seq[((size_t)(b * S + xidx) << 9) + col] = hnew;   // normal store
      if (gru == 2 && s == seqlen - 1) qbuf[((size_t)b << 9) + col] = hnew;
    }

    if (s + 1 < seqlen) {
      const int xidx2 = rev ? (seqlen - 2 - s) : (s + 1);
      float nxr[4], nxz[4], nxn[4];
#pragma unroll
      for (int j = 0; j < 4; ++j) {
        const int b = (ib << 4) + (lk << 2) + j;
        const size_t gxrow = ((size_t)b * seqlen + xidx2) * 1536;
        nxr[j] = gx[gxrow + col];
        nxz[j] = gx[gxrow + 512 + col];
        nxn[j] = gx[gxrow + 1024 + col];
      }
      flag_barrier(flags, rank, (unsigned)(s + 1), t, lane, wv);
#pragma unroll
      for (int j = 0; j < 4; ++j) { xr[j] = nxr[j]; xz[j] = nxz[j]; xn[j] = nxn[j]; }
    }
  }
}

// ---------------------------------------------------------------------------
// MFMA persistent AGRU scan, round-10: bf16 C exchange, f32 carry in regs,
// final step writes f32 C0 for the downstream GEMM. 32 WGs = 4 groups x 8.
// ---------------------------------------------------------------------------
__global__ __launch_bounds__(256, 1) void k_agru_scan_mfma(
    const float* __restrict__ UrT, const float* __restrict__ UT,
    const float* __restrict__ fRW, const float* __restrict__ fW,
    const float* __restrict__ br, const float* __restrict__ G,
    ushort_t* __restrict__ C16, float* __restrict__ C0f,
    unsigned* __restrict__ flags_base) {
  const int bx   = blockIdx.x;     // 32
  const int grp  = bx >> 3;        // 0..3 (16 items each)
  const int rank = bx & 7;
  ushort_t* Cb0 = C16;             // [64][512] bf16, parity 0
  ushort_t* Cb1 = C16 + 32768;

  __shared__ __align__(16) ushort_t cl[16 * 520];

  const int t    = threadIdx.x;
  const int lane = t & 63;
  const int wv   = t >> 6;
  const int nt   = (rank << 2) + wv;
  const int lm   = lane & 15;
  const int lk   = lane >> 4;
  const int col  = (nt << 4) + lm;

  bf16x8 wfr[16], wfu[16];
  {
    const float* r0 = UrT + ((size_t)col << 9) + (lk << 3);
    const float* r1 = UT  + ((size_t)col << 9) + (lk << 3);
#pragma unroll
    for (int ks = 0; ks < 16; ++ks) {
      wfr[ks] = pack8(*(const f32x4*)(r0 + ks * 32), *(const f32x4*)(r0 + ks * 32 + 4));
      wfu[ks] = pack8(*(const f32x4*)(r1 + ks * 32), *(const f32x4*)(r1 + ks * 32 + 4));
    }
  }
  const float brv = br[col];
  unsigned* flags = flags_base + grp * 8 * 32;

  float fr[4], fw[4], gg[4];
#pragma unroll
  for (int j = 0; j < 4; ++j) {
    const int b = (grp << 4) + (lk << 2) + j;
    const size_t fi = ((size_t)(b * S) << 9) + col;
    fr[j] = fRW[fi];
    fw[j] = fW[fi];
    gg[j] = G[b << 6];
  }

  float cp[4] = {0.f, 0.f, 0.f, 0.f};

  for (int s = 0; s < S; ++s) {
    if (s == 0) {
      for (int i = t; i < 4160; i += 256) ((unsigned*)cl)[i] = 0u;
    } else {
      const ushort_t* Cp16 = (s & 1) ? Cb1 : Cb0;
      u32x4 v[4];
#pragma unroll
      for (int u = 0; u < 4; ++u) {
        const int i = (u << 8) + t;
        v[u] = load16c(Cp16 + ((size_t)((grp << 4) + (i >> 6)) << 9) + ((i << 3) & 511));
      }
      waitvm0();
#pragma unroll
      for (int u = 0; u < 4; ++u) {
        const int i = (u << 8) + t;
        *(u32x4*)&cl[(i >> 6) * 520 + ((i << 3) & 511)] = v[u];
      }
    }
    __syncthreads();

    f32x4 accr = {}, accu = {};
#pragma unroll
    for (int ks = 0; ks < 16; ++ks) {
      const bf16x8 a = *(const bf16x8*)&cl[lm * 520 + (ks << 5) + (lk << 3)];
      accr = __builtin_amdgcn_mfma_f32_16x16x32_bf16(a, wfr[ks], accr, 0, 0, 0);
      accu = __builtin_amdgcn_mfma_f32_16x16x32_bf16(a, wfu[ks], accu, 0, 0, 0);
    }

    ushort_t* Cn16 = (s & 1) ? Cb0 : Cb1;
#pragma unroll
    for (int j = 0; j < 4; ++j) {
      const int b = (grp << 4) + (lk << 2) + j;
      const float r  = sigm(fr[j] + accr[j] + brv);
      const float ht = tanhf(fw[j] + r * accu[j] + brv);
      const float cnew = gg[j] * ht + (1.f - gg[j]) * cp[j];
      cp[j] = cnew;
      if (s + 1 < S) store2c(Cn16 + ((size_t)b << 9) + col, (unsigned)f2bf(cnew));
      else           C0f[((size_t)b << 9) + col] = cnew;   // final hop state, f32
    }

    if (s + 1 < S) {
      float nfr[4], nfw[4], ngg[4];
#pragma unroll
      for (int j = 0; j < 4; ++j) {
        const int b = (grp << 4) + (lk << 2) + j;
        const size_t fi = ((size_t)(b * S + s + 1) << 9) + col;
        nfr[j] = fRW[fi];
        nfw[j] = fW[fi];
        ngg[j] = G[(b << 6) + s + 1];
      }
      flag_barrier(flags, rank, (unsigned)(s + 1), t, lane, wv);
#pragma unroll
      for (int j = 0; j < 4; ++j) { fr[j] = nfr[j]; fw[j] = nfw[j]; gg[j] = ngg[j]; }
    }
  }
}

__global__ __launch_bounds__(256) void k_add(float* __restrict__ a, const float* __restrict__ b) {
  const size_t i = (((size_t)blockIdx.x << 8) + threadIdx.x) << 2;
  float4 x = *(float4*)(a + i);
  const float4 y = *(const float4*)(b + i);
  x.x += y.x; x.y += y.y; x.z += y.z; x.w += y.w;
  *(float4*)(a + i) = x;
}

__global__ __launch_bounds__(256) void k_score_softmax(const float* __restrict__ g1,
                                                       const float* __restrict__ z2w,
                                                       const float* __restrict__ z2b,
                                                       float* __restrict__ G) {
  const int b = blockIdx.x, t = threadIdx.x;
  const int wave = t >> 6, lane = t & 63;
  __shared__ float sc[64];
  for (int si = 0; si < 16; ++si) {
    const int s = wave * 16 + si;
    const float* row = g1 + ((size_t)(b * S + s) << 9) + lane * 8;
    const float* w   = z2w + lane * 8;
    float p = 0.f;
#pragma unroll
    for (int k = 0; k < 8; ++k) p += row[k] * w[k];
#pragma unroll
    for (int off = 32; off; off >>= 1) p += __shfl_xor(p, off);
    if (lane == 0) sc[s] = p + z2b[0];
  }
  __syncthreads();
  if (wave == 0) {
    const float v = sc[lane];
    float m = v;
#pragma unroll
    for (int off = 32; off; off >>= 1) m = fmaxf(m, __shfl_xor(m, off));
    const float e = expf(v - m);
    float su = e;
#pragma unroll
    for (int off = 32; off; off >>= 1) su += __shfl_xor(su, off);
    G[(b << 6) + lane] = e / su;
  }
}

}  // namespace

extern "C" void kernel_launch(void* const* d_in, const int* in_sizes, int n_in,
                              void* d_out, int out_size, void* d_ws, size_t ws_size,
                              hipStream_t stream) {
  const int*   contexts  = (const int*)d_in[0];
  const int*   questions = (const int*)d_in[1];
  const float* emb   = (const float*)d_in[2];
  const float* Wih_f = (const float*)d_in[3];
  const float* Whh_f = (const float*)d_in[4];
  const float* bih_f = (const float*)d_in[5];
  const float* bhh_f = (const float*)d_in[6];
  const float* Wih_b = (const float*)d_in[7];
  const float* Whh_b = (const float*)d_in[8];
  const float* bih_b = (const float*)d_in[9];
  const float* bhh_b = (const float*)d_in[10];
  const float* qWih  = (const float*)d_in[11];
  const float* qWhh  = (const float*)d_in[12];
  const float* qbih  = (const float*)d_in[13];
  const float* qbhh  = (const float*)d_in[14];
  const float* Wr    = (const float*)d_in[15];
  const float* Ur    = (const float*)d_in[16];
  const float* br    = (const float*)d_in[17];
  const float* Wm    = (const float*)d_in[18];
  const float* Um    = (const float*)d_in[19];
  const float* z1_w  = (const float*)d_in[20];
  const float* z1_b  = (const float*)d_in[21];
  const float* z2_w  = (const float*)d_in[22];
  const float* z2_b  = (const float*)d_in[23];
  const float* nm_w  = (const float*)d_in[24];
  const float* nm_b  = (const float*)d_in[25];
  const float* ans_w = (const float*)d_in[26];
  const float* ans_b = (const float*)d_in[27];
  (void)in_sizes; (void)n_in; (void)out_size; (void)ws_size;

  float* ws = (float*)d_ws;
  float* WrT      = ws + 0;          // 262144
  float* UrT      = ws + 262144;     // 262144
  float* WT       = ws + 524288;     // 262144
  float* UT       = ws + 786432;     // 262144
  float* facts_in = ws + 1048576;    // 2097152  (reused as fRW)
  float* qe       = ws + 3145728;    // 1048576
  float* gx_f     = ws + 4194304;    // 6291456  (reused as zb16 in hops)
  float* gx_b     = ws + 10485760;   // 6291456
  float* gx_q     = ws + 16777216;   // 3145728  (reused as g1)
  float* facts    = ws + 19922944;   // 2097152
  float* hb       = ws + 22020096;   // 2097152  (reused as fW)
  float* Hbuf     = ws + 24117248;   // 196608 floats: H16/q/C16 live here
  float* C0       = ws + 24313856;   // 32768 (final AGRU state, f32)
  float* M0       = ws + 24379392;   // 32768
  float* M1       = ws + 24412160;   // 32768
  float* Mq       = ws + 24543232;   // flags region
  float* Gm       = ws + 24608768;   // 4096
  ushort_t* H16 = (ushort_t*)Hbuf;             // 3 GRUs x 2 x [64][512] bf16 (98304 fl)
  float* qbuf   = Hbuf + 98304;                // 32768 floats (question state)
  ushort_t* C16 = (ushort_t*)(Hbuf + 131072);  // 2 x [64][512] bf16 (32768 fl)
  ushort_t* zb16 = (ushort_t*)gx_f;            // 4096x2048 bf16
  float* g1  = gx_q;
  float* fRW = facts_in;
  float* fW  = hb;
  float* preds = (float*)d_out;
  unsigned* bar = (unsigned*)Mq;     // flags: GRU 12*256 + 3 hops * 4*256 = 6144 u32
  float* q = qbuf;

  // ---- flags: zero once per call (monotone counters) ----
  hipMemsetAsync(bar, 0, 6144 * sizeof(unsigned), stream);

  // ---- stage A: embeddings + weight transposes ----
  k_embed_facts<<<B * S, 256, 0, stream>>>(contexts, emb, facts_in);
  k_embed_q<<<B * TQ, 256, 0, stream>>>(questions, emb, qe);
  dim3 tb(32, 8);
  k_transpose512<<<dim3(16, 16), tb, 0, stream>>>(Wr, WrT);
  k_transpose512<<<dim3(16, 16), tb, 0, stream>>>(Ur, UrT);
  k_transpose512<<<dim3(16, 16), tb, 0, stream>>>(Wm, WT);
  k_transpose512<<<dim3(16, 16), tb, 0, stream>>>(Um, UT);

  // ---- stage B: input-side gate GEMMs (bf16 MFMA) ----
  k_gemm_mfma<false, 0><<<dim3(24, 64), 256, 0, stream>>>(facts_in, Wih_f, bih_f, gx_f, 4096, 1536, 512);
  k_gemm_mfma<false, 0><<<dim3(24, 64), 256, 0, stream>>>(facts_in, Wih_b, bih_b, gx_b, 4096, 1536, 512);
  k_gemm_mfma<false, 0><<<dim3(24, 32), 256, 0, stream>>>(qe, qWih, qbih, gx_q, 2048, 1536, 512);

  // ---- stage C: MFMA persistent GRU scans (plain launch, 96 WGs) ----
  k_gru_scan_mfma<<<96, 256, 0, stream>>>(Whh_f, bhh_f, Whh_b, bhh_b, qWhh, qbhh,
                                          gx_f, gx_b, gx_q, H16, qbuf, facts, hb, bar);
  k_add<<<2048, 256, 0, stream>>>(facts, hb);

  // ---- stage D: hop-invariant precomputes (bf16 MFMA) ----
  k_gemm_mfma<false, 0><<<dim3(8, 64), 256, 0, stream>>>(facts, WrT, nullptr, fRW, 4096, 512, 512);
  k_gemm_mfma<false, 0><<<dim3(8, 64), 256, 0, stream>>>(facts, WT,  nullptr, fW,  4096, 512, 512);

  // ---- stage E: episodic memory hops (z1 reverted to round-8 path) ----
  const float* Mcur = q;
  for (int h = 0; h < 3; ++h) {
    k_build_z16<<<B * S, 256, 0, stream>>>(facts, q, Mcur, zb16);
    k_gemm_mfma<true, 1><<<dim3(8, 64), 256, 0, stream>>>(zb16, z1_w, z1_b, g1, 4096, 512, 2048);
    k_score_softmax<<<B, 256, 0, stream>>>(g1, z2_w, z2_b, Gm);
    unsigned* fl = bar + 3072 + h * 1024;
    k_agru_scan_mfma<<<32, 256, 0, stream>>>(UrT, UT, fRW, fW, br, Gm, C16, C0, fl);
    float* Mnext = (h & 1) ? M1 : M0;
    k_gemm_cat3<<<dim3(8, 1), 256, 0, stream>>>(Mcur, C0, q, nm_w, nm_b, Mnext);
    Mcur = Mnext;
  }

  // ---- stage F: answer projection (fused concat2) ----
  k_gemm_cat2<<<dim3(500, 1), 256, 0, stream>>>(Mcur, q, ans_w, ans_b, preds);
}